// Round 1
// baseline (252.688 us; speedup 1.0000x reference)
//
#include <hip/hip_runtime.h>
#include <hip/hip_fp16.h>

// Problem constants (fixed by setup_inputs)
#define B_ 4096
#define D_ 256
#define N_ 8192           // 2*B
#define K_TOP 2047        // (N-2)/4
#define NBINS 2048
#define LISTCAP 2048
#define RCPT 14.285714285714286f  // 1/0.07

typedef _Float16 half8 __attribute__((ext_vector_type(8)));
typedef _Float16 half4v __attribute__((ext_vector_type(4)));
typedef float floatx4 __attribute__((ext_vector_type(4)));

// ---------------- normalize: fp32 rows -> normalized fp32 + fp16 copies ----
__global__ __launch_bounds__(256) void normalize_kernel(
    const float* __restrict__ ei, const float* __restrict__ ej,
    float* __restrict__ E32, _Float16* __restrict__ E16,
    float* __restrict__ out) {
  if (blockIdx.x == 0 && threadIdx.x == 0) out[0] = 0.f;  // init accumulator
  int w = threadIdx.x >> 6, lane = threadIdx.x & 63;
  int row = blockIdx.x * 4 + w;
  const float* src = (row < B_) ? (ei + (size_t)row * D_)
                                : (ej + (size_t)(row - B_) * D_);
  float4 v = ((const float4*)src)[lane];  // 64 lanes x 4 floats = 256 = D
  float ss = v.x * v.x + v.y * v.y + v.z * v.z + v.w * v.w;
  #pragma unroll
  for (int off = 32; off > 0; off >>= 1) ss += __shfl_down(ss, off);
  ss = __shfl(ss, 0);
  float sc = 1.0f / fmaxf(sqrtf(ss), 1e-12f);
  v.x *= sc; v.y *= sc; v.z *= sc; v.w *= sc;
  ((float4*)(E32 + (size_t)row * D_))[lane] = v;
  half4v h; h[0] = (_Float16)v.x; h[1] = (_Float16)v.y;
  h[2] = (_Float16)v.z; h[3] = (_Float16)v.w;
  *(half4v*)(E16 + (size_t)row * D_ + lane * 4) = h;
}

// ---------------- positive-pair dots in fp32 -------------------------------
__global__ __launch_bounds__(256) void pdots_kernel(
    const float* __restrict__ E32, float* __restrict__ p) {
  int w = threadIdx.x >> 6, lane = threadIdx.x & 63;
  int row = blockIdx.x * 4 + w;
  int pr = (row + B_) & (N_ - 1);
  float4 a = ((const float4*)(E32 + (size_t)row * D_))[lane];
  float4 b = ((const float4*)(E32 + (size_t)pr * D_))[lane];
  float d = a.x * b.x + a.y * b.y + a.z * b.z + a.w * b.w;
  #pragma unroll
  for (int off = 32; off > 0; off >>= 1) d += __shfl_down(d, off);
  if (lane == 0) p[row] = d * RCPT;
}

// ---------------- S = (E E^T) / T in fp16, MFMA 16x16x32 f16 ---------------
#define TS 128
#define BK 64
#define LDP 72   // 64 + 8 halfs pad -> stride 144B, 2-way LDS conflicts only
__global__ __launch_bounds__(256) void gemm_kernel(
    const _Float16* __restrict__ E, _Float16* __restrict__ S) {
  __shared__ __align__(16) _Float16 As[TS][LDP];
  __shared__ __align__(16) _Float16 Bs[TS][LDP];
  int bx = blockIdx.x;
  int tm = bx >> 6, tn = bx & 63;
  int m0 = tm * TS, n0 = tn * TS;
  int t = threadIdx.x, w = t >> 6, lane = t & 63;
  int quad = lane >> 4, l16 = lane & 15;
  int wr = (w & 1) * 64, wc = (w >> 1) * 64;
  floatx4 zero = {0.f, 0.f, 0.f, 0.f};
  floatx4 acc[4][4];
  #pragma unroll
  for (int a = 0; a < 4; ++a)
    #pragma unroll
    for (int b = 0; b < 4; ++b) acc[a][b] = zero;

  for (int kb = 0; kb < D_; kb += BK) {
    __syncthreads();
    for (int cc = t; cc < 1024; cc += 256) {      // 128 rows x 8 chunks of 16B
      int rr = cc >> 3, co = (cc & 7) << 3;
      *(float4*)(&As[rr][co]) =
          *(const float4*)(E + (size_t)(m0 + rr) * D_ + kb + co);
      *(float4*)(&Bs[rr][co]) =
          *(const float4*)(E + (size_t)(n0 + rr) * D_ + kb + co);
    }
    __syncthreads();
    #pragma unroll
    for (int ks = 0; ks < BK; ks += 32) {
      half8 aF[4], bF[4];
      #pragma unroll
      for (int ti = 0; ti < 4; ++ti)
        aF[ti] = *(const half8*)(&As[wr + ti * 16 + l16][ks + quad * 8]);
      #pragma unroll
      for (int tj = 0; tj < 4; ++tj)
        bF[tj] = *(const half8*)(&Bs[wc + tj * 16 + l16][ks + quad * 8]);
      #pragma unroll
      for (int ti = 0; ti < 4; ++ti)
        #pragma unroll
        for (int tj = 0; tj < 4; ++tj)
          acc[ti][tj] = __builtin_amdgcn_mfma_f32_16x16x32_f16(
              aF[ti], bF[tj], acc[ti][tj], 0, 0, 0);
    }
  }
  // C/D layout: col = lane&15, row = quad*4 + reg  (m89-verified)
  #pragma unroll
  for (int ti = 0; ti < 4; ++ti)
    #pragma unroll
    for (int tj = 0; tj < 4; ++tj)
      #pragma unroll
      for (int rg = 0; rg < 4; ++rg) {
        int row = m0 + wr + ti * 16 + quad * 4 + rg;
        int col = n0 + wc + tj * 16 + l16;
        S[(size_t)row * N_ + col] = (_Float16)(acc[ti][tj][rg] * RCPT);
      }
}

// ---------------- per-row: histogram top-k + exp sums ----------------------
__global__ __launch_bounds__(256) void row_kernel(
    const _Float16* __restrict__ S, const float* __restrict__ p,
    float* __restrict__ out) {
  __shared__ __align__(16) _Float16 rowv[N_];   // 16 KB
  __shared__ unsigned hist[NBINS];              // 8 KB
  __shared__ float blist[LISTCAP];              // 8 KB
  __shared__ unsigned sbuf[256];
  __shared__ unsigned s_bstar, s_nabove, s_cnt;
  __shared__ float s_red[4];
  int i = blockIdx.x, t = threadIdx.x;
  int posi = (i + B_) & (N_ - 1);

  for (int b = t; b < NBINS; b += 256) hist[b] = 0;
  if (t == 0) s_cnt = 0;
  {  // load row (fp16, coalesced float4)
    const float4* Sr = (const float4*)(S + (size_t)i * N_);
    float4* Rv = (float4*)rowv;
    #pragma unroll
    for (int j = 0; j < 4; ++j) Rv[t + j * 256] = Sr[t + j * 256];
  }
  __syncthreads();

  const float lo = -14.5f;
  const float invw = (float)NBINS / 29.0f;
  // pass 1: histogram of negatives
  for (int j = 0; j < 32; ++j) {
    int c = t + (j << 8);
    if (c == i || c == posi) continue;
    float s = (float)rowv[c];
    int b = (int)((s - lo) * invw);
    b = max(0, min(NBINS - 1, b));
    atomicAdd(&hist[b], 1u);
  }
  __syncthreads();
  // suffix scan (from top bins) to find bin of the K_TOP-th largest
  unsigned cs = 0;
  #pragma unroll
  for (int q = 0; q < 8; ++q) cs += hist[t * 8 + q];
  sbuf[t] = cs;
  __syncthreads();
  for (int off = 1; off < 256; off <<= 1) {
    unsigned addv = (t + off < 256) ? sbuf[t + off] : 0u;
    __syncthreads();
    sbuf[t] += addv;
    __syncthreads();
  }
  unsigned incl = sbuf[t];         // sum over chunks >= t
  unsigned above = incl - cs;      // values in bins above this chunk
  if (above < K_TOP && incl >= K_TOP) {  // exactly one thread
    unsigned cum = above;
    for (int b = t * 8 + 7; b >= t * 8; --b) {
      unsigned h = hist[b];
      if (cum + h >= K_TOP) { s_bstar = (unsigned)b; s_nabove = cum; break; }
      cum += h;
    }
  }
  __syncthreads();
  int bstar = (int)s_bstar;
  unsigned r = K_TOP - s_nabove;   // take r values from boundary bin

  // pass 2: sums + boundary-bin collection
  float part = 0.f;
  for (int j = 0; j < 32; ++j) {
    int c = t + (j << 8);
    if (c == i || c == posi) continue;
    float s = (float)rowv[c];
    int b = (int)((s - lo) * invw);
    b = max(0, min(NBINS - 1, b));
    part += __expf(s);                         // all negatives
    if (b > bstar) part += __expf(2.f * s);    // definitely in top-k
    else if (b == bstar) {
      unsigned idx = atomicAdd(&s_cnt, 1u);
      if (idx < LISTCAP) blist[idx] = s;
    }
  }
  __syncthreads();
  // exact selection among boundary-bin values via parallel ranking
  unsigned cnt = s_cnt; if (cnt > LISTCAP) cnt = LISTCAP;
  for (unsigned e = t; e < cnt; e += 256) {
    float v = blist[e];
    unsigned rank = 0;
    for (unsigned q = 0; q < cnt; ++q) {
      float u = blist[q];
      rank += (unsigned)((u > v) || (u == v && q < e));
    }
    if (rank < r) part += __expf(2.f * v);
  }
  // reduce
  #pragma unroll
  for (int off = 32; off > 0; off >>= 1) part += __shfl_down(part, off);
  if ((t & 63) == 0) s_red[t >> 6] = part;
  __syncthreads();
  if (t == 0) {
    float tot = s_red[0] + s_red[1] + s_red[2] + s_red[3];
    float pi = p[i];
    tot += __expf(pi);
    float loss = -pi + logf(tot);
    atomicAdd(out, loss * (1.0f / (float)N_));
  }
}

// ---------------- launch ---------------------------------------------------
extern "C" void kernel_launch(void* const* d_in, const int* in_sizes, int n_in,
                              void* d_out, int out_size, void* d_ws,
                              size_t ws_size, hipStream_t stream) {
  const float* ei = (const float*)d_in[0];
  const float* ej = (const float*)d_in[1];
  float* out = (float*)d_out;
  char* ws = (char*)d_ws;
  // workspace layout (needs ~147 MB)
  _Float16* S = (_Float16*)ws;                                  // 134,217,728 B
  float* E32 = (float*)(ws + 134217728);                        //   8,388,608 B
  _Float16* E16 = (_Float16*)(ws + 134217728 + 8388608);        //   4,194,304 B
  float* p = (float*)(ws + 134217728 + 8388608 + 4194304);      //      32,768 B

  normalize_kernel<<<N_ / 4, 256, 0, stream>>>(ei, ej, E32, E16, out);
  pdots_kernel<<<N_ / 4, 256, 0, stream>>>(E32, p);
  gemm_kernel<<<(N_ / TS) * (N_ / TS), 256, 0, stream>>>(E16, S);
  row_kernel<<<N_, 256, 0, stream>>>(S, p, out);
}